// Round 9
// baseline (435.868 us; speedup 1.0000x reference)
//
#include <hip/hip_runtime.h>
#include <hip/hip_bf16.h>

#define H_   2048
#define E_   8
#define T_   1024
#define TWOI 4096
#define I_   2048
#define ALPHA 1.702f
#define LIMIT 7.0f

#define BM 128
#define BN 128
#define BKK 32
#define BTW 40   // bf16 B^T row length: 32 + 8 pad (80 B, 16B-aligned)

typedef __attribute__((ext_vector_type(8))) short short8;
typedef __attribute__((ext_vector_type(4))) float f32x4;

#define AS3U(p) ((__attribute__((address_space(3))) unsigned int*)(p))
#define AS1U(p) ((const __attribute__((address_space(1))) unsigned int*)(p))

__device__ __forceinline__ unsigned short f2bf(float f) {
    unsigned int u = __float_as_uint(f);
    u += 0x7fff + ((u >> 16) & 1);   // RTNE
    return (unsigned short)(u >> 16);
}

__device__ __forceinline__ unsigned int cvtpk_bf16(float lo, float hi) {
    unsigned int r;
    asm("v_cvt_pk_bf16_f32 %0, %1, %2" : "=v"(r) : "v"(lo), "v"(hi));
    return r;
}

// ---------------------------------------------------------------- zero
__global__ void zero_kernel(float* __restrict__ out, int n, int* __restrict__ counts) {
    int i = blockIdx.x * blockDim.x + threadIdx.x;
    if (i < n) out[i] = 0.0f;
    if (i < E_) counts[i] = 0;
}

// ---------------------------------------------------------------- rmsnorm + router
__global__ __launch_bounds__(256) void rms_router(
    const float* __restrict__ x, const float* __restrict__ nw,
    const float* __restrict__ rw,
    unsigned short* __restrict__ tbf, int* __restrict__ counts,
    int* __restrict__ tlist, float* __restrict__ tw)
{
    int t = blockIdx.x;
    int tid = threadIdx.x;
    int wave = tid >> 6, lane = tid & 63;
    const float* xr = x + (size_t)t * H_;

    float4 v0 = *(const float4*)(xr + tid * 4);
    float4 v1 = *(const float4*)(xr + 1024 + tid * 4);
    float ss = v0.x*v0.x + v0.y*v0.y + v0.z*v0.z + v0.w*v0.w
             + v1.x*v1.x + v1.y*v1.y + v1.z*v1.z + v1.w*v1.w;
    #pragma unroll
    for (int s = 32; s; s >>= 1) ss += __shfl_xor(ss, s);

    __shared__ float red[4];
    __shared__ float wlog[4][8];
    if (lane == 0) red[wave] = ss;
    __syncthreads();
    float total = red[0] + red[1] + red[2] + red[3];
    float scale = rsqrtf(total * (1.0f / H_) + 1e-5f);

    float4 n0 = *(const float4*)(nw + tid * 4);
    float4 n1 = *(const float4*)(nw + 1024 + tid * 4);
    float tv[8];
    tv[0] = v0.x * scale * n0.x; tv[1] = v0.y * scale * n0.y;
    tv[2] = v0.z * scale * n0.z; tv[3] = v0.w * scale * n0.w;
    tv[4] = v1.x * scale * n1.x; tv[5] = v1.y * scale * n1.y;
    tv[6] = v1.z * scale * n1.z; tv[7] = v1.w * scale * n1.w;

    ushort4 o0 = make_ushort4(f2bf(tv[0]), f2bf(tv[1]), f2bf(tv[2]), f2bf(tv[3]));
    ushort4 o1 = make_ushort4(f2bf(tv[4]), f2bf(tv[5]), f2bf(tv[6]), f2bf(tv[7]));
    *(ushort4*)(tbf + (size_t)t * H_ + tid * 4) = o0;
    *(ushort4*)(tbf + (size_t)t * H_ + 1024 + tid * 4) = o1;

    float acc[E_];
    #pragma unroll
    for (int e = 0; e < E_; e++) {
        const float* r0 = rw + (size_t)e * H_ + tid * 4;
        float4 a = *(const float4*)r0;
        float4 b = *(const float4*)(r0 + 1024);
        acc[e] = tv[0]*a.x + tv[1]*a.y + tv[2]*a.z + tv[3]*a.w
               + tv[4]*b.x + tv[5]*b.y + tv[6]*b.z + tv[7]*b.w;
    }
    #pragma unroll
    for (int s = 32; s; s >>= 1)
        #pragma unroll
        for (int e = 0; e < E_; e++) acc[e] += __shfl_xor(acc[e], s);
    if (lane == 0)
        #pragma unroll
        for (int e = 0; e < E_; e++) wlog[wave][e] = acc[e];
    __syncthreads();

    if (tid == 0) {
        float lg[E_];
        #pragma unroll
        for (int e = 0; e < E_; e++)
            lg[e] = wlog[0][e] + wlog[1][e] + wlog[2][e] + wlog[3][e];
        int i0 = 0;
        #pragma unroll
        for (int e = 1; e < E_; e++) if (lg[e] > lg[i0]) i0 = e;
        int i1 = -1;
        #pragma unroll
        for (int e = 0; e < E_; e++) {
            if (e == i0) continue;
            if (i1 < 0 || lg[e] > lg[i1]) i1 = e;
        }
        float e1 = expf(lg[i1] - lg[i0]);
        float s = 1.0f + e1;
        float w0 = 1.0f / s, w1 = e1 / s;
        int p0 = atomicAdd(&counts[i0], 1);
        tlist[i0 * T_ + p0] = t; tw[i0 * T_ + p0] = w0;
        int p1 = atomicAdd(&counts[i1], 1);
        tlist[i1 * T_ + p1] = t; tw[i1 * T_ + p1] = w1;
    }
}

// ---------------------------------------------------------------- shared GEMM machinery
// A: bf16 [BM][32] linear. B^T: bf16 [BN][BTW]. Both fragment reads are ds_read_b128.
__device__ __forceinline__ void compute_step(
    const unsigned short (*Asb)[BKK], const unsigned short (*Btb)[BTW],
    int wm, int wn, int lane, f32x4 acc[4][4])
{
    short8 a[4], b[4];
    int arow = wm * 64 + (lane & 15);
    int brow = wn * 64 + (lane & 15);
    int koff = (lane >> 4) * 8;
    #pragma unroll
    for (int mi = 0; mi < 4; mi++)
        a[mi] = *(const short8*)(&Asb[arow + mi * 16][koff]);
    #pragma unroll
    for (int ni = 0; ni < 4; ni++)
        b[ni] = *(const short8*)(&Btb[brow + ni * 16][koff]);
    #pragma unroll
    for (int mi = 0; mi < 4; mi++)
        #pragma unroll
        for (int ni = 0; ni < 4; ni++)
            acc[mi][ni] = __builtin_amdgcn_mfma_f32_16x16x32_bf16(a[mi], b[ni], acc[mi][ni], 0, 0, 0);
}

// Depth-3 pipelined K-step. A: 4 LDS buffers, DMA 3 tiles ahead. B: 3 register
// sets, global loads 3 tiles ahead, bf16 ds_write one step before use.
// 18 VMEM ops per tile-set (2 global_load_lds + 16 B dwords); steady-state
// vmcnt(36) keeps two full tile-sets in flight across every barrier.
// MODE: 2 = prefetch + vmcnt(36); 1 = no prefetch, vmcnt(18); 0 = vmcnt(0).
#define STEP(TT, RCUR, RNEXT, MODE) {                                              \
    if ((MODE) == 2) {                                                             \
        int kk3_ = ((TT) + 3) * BKK;                                               \
        __builtin_amdgcn_global_load_lds(AS1U(asrc0 + kk3_), AS3U(&As[c3][wave * 32][0]), 16, 0, 0);      \
        __builtin_amdgcn_global_load_lds(AS1U(asrc1 + kk3_), AS3U(&As[c3][wave * 32 + 16][0]), 16, 0, 0); \
        _Pragma("unroll")                                                          \
        for (int j = 0; j < 16; j++)                                               \
            RNEXT[j] = bcol[(size_t)(kk3_ + sk + j) * ldbv];                       \
    }                                                                              \
    compute_step(As[c0], Bt[(TT) & 1], wm, wn, lane, acc);                         \
    {                                                                              \
        unsigned int pk_[8];                                                       \
        _Pragma("unroll")                                                          \
        for (int h = 0; h < 8; h++) pk_[h] = cvtpk_bf16(RCUR[2 * h], RCUR[2 * h + 1]); \
        unsigned short* db_ = &Bt[((TT) + 1) & 1][sn][sk];                         \
        *(uint4*)(db_)     = make_uint4(pk_[0], pk_[1], pk_[2], pk_[3]);           \
        *(uint4*)(db_ + 8) = make_uint4(pk_[4], pk_[5], pk_[6], pk_[7]);           \
    }                                                                              \
    if ((MODE) == 2)      { asm volatile("s_waitcnt vmcnt(36)" ::: "memory"); }    \
    else if ((MODE) == 1) { asm volatile("s_waitcnt vmcnt(18)" ::: "memory"); }    \
    else                  { asm volatile("s_waitcnt vmcnt(0)"  ::: "memory"); }    \
    asm volatile("s_waitcnt lgkmcnt(0)" ::: "memory");                             \
    __builtin_amdgcn_sched_barrier(0);                                             \
    __builtin_amdgcn_s_barrier();                                                  \
    __builtin_amdgcn_sched_barrier(0);                                             \
    { int tmp_ = c0; c0 = c1; c1 = c2; c2 = c3; c3 = tmp_; }                       \
}

// Full pipeline over NS K-steps. NS must be 64 or 32 (literal).
#define GEMM_PIPELINE(NS)                                                          \
    float r0[16], r1[16], r2[16];                                                  \
    int c0 = 0, c1 = 1, c2 = 2, c3 = 3;                                            \
    /* prologue: tiles 0,1,2 in flight; write B(0) */                              \
    __builtin_amdgcn_global_load_lds(AS1U(asrc0), AS3U(&As[0][wave * 32][0]), 16, 0, 0);                \
    __builtin_amdgcn_global_load_lds(AS1U(asrc1), AS3U(&As[0][wave * 32 + 16][0]), 16, 0, 0);           \
    _Pragma("unroll")                                                              \
    for (int j = 0; j < 16; j++) r0[j] = bcol[(size_t)(sk + j) * ldbv];            \
    __builtin_amdgcn_global_load_lds(AS1U(asrc0 + BKK), AS3U(&As[1][wave * 32][0]), 16, 0, 0);          \
    __builtin_amdgcn_global_load_lds(AS1U(asrc1 + BKK), AS3U(&As[1][wave * 32 + 16][0]), 16, 0, 0);     \
    _Pragma("unroll")                                                              \
    for (int j = 0; j < 16; j++) r1[j] = bcol[(size_t)(BKK + sk + j) * ldbv];      \
    __builtin_amdgcn_global_load_lds(AS1U(asrc0 + 2 * BKK), AS3U(&As[2][wave * 32][0]), 16, 0, 0);      \
    __builtin_amdgcn_global_load_lds(AS1U(asrc1 + 2 * BKK), AS3U(&As[2][wave * 32 + 16][0]), 16, 0, 0); \
    _Pragma("unroll")                                                              \
    for (int j = 0; j < 16; j++) r2[j] = bcol[(size_t)(2 * BKK + sk + j) * ldbv];  \
    {                                                                              \
        unsigned int pk_[8];                                                       \
        _Pragma("unroll")                                                          \
        for (int h = 0; h < 8; h++) pk_[h] = cvtpk_bf16(r0[2 * h], r0[2 * h + 1]); \
        unsigned short* db_ = &Bt[0][sn][sk];                                      \
        *(uint4*)(db_)     = make_uint4(pk_[0], pk_[1], pk_[2], pk_[3]);           \
        *(uint4*)(db_ + 8) = make_uint4(pk_[4], pk_[5], pk_[6], pk_[7]);           \
    }                                                                              \
    asm volatile("s_waitcnt vmcnt(36)" ::: "memory");                              \
    asm volatile("s_waitcnt lgkmcnt(0)" ::: "memory");                             \
    __builtin_amdgcn_sched_barrier(0);                                             \
    __builtin_amdgcn_s_barrier();                                                  \
    __builtin_amdgcn_sched_barrier(0);                                             \
    for (int t = 0; t < (((NS) - 3) / 3) * 3; t += 3) {                            \
        STEP(t,     r1, r0, 2)                                                     \
        STEP(t + 1, r2, r1, 2)                                                     \
        STEP(t + 2, r0, r2, 2)                                                     \
    }                                                                              \
    if ((NS) == 64) {                                                              \
        STEP(60, r1, r0, 2)                                                        \
        STEP(61, r2, r1, 1)                                                        \
        STEP(62, r0, r2, 0)                                                        \
    } else {                                                                       \
        STEP(27, r1, r0, 2)                                                        \
        STEP(28, r2, r1, 2)                                                        \
        STEP(29, r0, r2, 1)                                                        \
        STEP(30, r1, r0, 0)                                                        \
    }                                                                              \
    compute_step(As[c0], Bt[((NS) - 1) & 1], wm, wn, lane, acc);

// ---------------------------------------------------------------- GU GEMM + swiglu
__global__ __launch_bounds__(256, 3) void gu_gemm(
    const unsigned short* __restrict__ tbf,
    const float* __restrict__ wgu,
    const int* __restrict__ counts, const int* __restrict__ tlist,
    unsigned short* __restrict__ act)
{
    // Work-first ordering: mtile slowest; working blocks spread across XCDs;
    // mtile twins 256 apart -> same XCD (256 % 8 == 0) for B-panel L2 reuse.
    int bid = blockIdx.x;
    int mtile = bid >> 8;
    int rem = bid & 255;
    int e = rem >> 5;
    int n0 = (rem & 31) * BN;

    int cnt = counts[e];
    int m0 = mtile * BM;
    if (m0 >= cnt) return;

    __shared__ __align__(16) unsigned short As[4][BM][BKK];
    __shared__ __align__(16) unsigned short Bt[2][BN][BTW];

    int tid = threadIdx.x;
    int lane = tid & 63, wave = tid >> 6;
    int wm = wave >> 1, wn = wave & 1;

    int row0 = wave * 32 + (lane >> 2);
    int gr0 = m0 + row0, gr1 = gr0 + 16;
    int tok0 = tlist[e * T_ + (gr0 < cnt ? gr0 : 0)];
    int tok1 = tlist[e * T_ + (gr1 < cnt ? gr1 : 0)];
    const unsigned short* asrc0 = tbf + (size_t)tok0 * H_ + (lane & 3) * 8;
    const unsigned short* asrc1 = tbf + (size_t)tok1 * H_ + (lane & 3) * 8;

    // B column staging: thread covers column n0+sn, k-halves sk..sk+15
    int sn = tid & 127;
    int sk = (tid >> 7) * 16;
    const float* bcol = wgu + (size_t)e * H_ * TWOI + n0 + sn;
    const int ldbv = TWOI;

    f32x4 acc[4][4];
    #pragma unroll
    for (int mi = 0; mi < 4; mi++)
        #pragma unroll
        for (int ni = 0; ni < 4; ni++) acc[mi][ni] = (f32x4){0.f, 0.f, 0.f, 0.f};

    GEMM_PIPELINE(64)

    // epilogue: swiglu on column pairs (even=gate, odd=linear), write act bf16
    #pragma unroll
    for (int mi = 0; mi < 4; mi++) {
        #pragma unroll
        for (int ni = 0; ni < 4; ni++) {
            #pragma unroll
            for (int r = 0; r < 4; r++) {
                float v = acc[mi][ni][r];
                float p = __shfl_xor(v, 1);
                int rowe = wm * 64 + mi * 16 + (lane >> 4) * 4 + r;
                int grow = m0 + rowe;
                if (!(lane & 1) && grow < cnt) {
                    float glu = fminf(v, LIMIT);
                    float lin = fminf(fmaxf(p, -LIMIT), LIMIT);
                    float g = glu / (1.0f + __expf(-ALPHA * glu));
                    float a_ = g * (lin + 1.0f);
                    int col = n0 + wn * 64 + ni * 16 + (lane & 15);
                    act[((size_t)e * T_ + grow) * I_ + (col >> 1)] = f2bf(a_);
                }
            }
        }
    }
}

// ---------------------------------------------------------------- DOWN GEMM + scatter (K-split x2)
__global__ __launch_bounds__(256, 3) void down_gemm(
    const unsigned short* __restrict__ act,
    const float* __restrict__ wdn,
    const int* __restrict__ counts, const int* __restrict__ tlist,
    const float* __restrict__ tw, float* __restrict__ out)
{
    // Work-first ordering: mtile slowest; (e, ks, nt) fast.
    int bid = blockIdx.x;
    int mtile = bid >> 8;
    int rem = bid & 255;
    int e = rem >> 5;
    int ks = (rem >> 4) & 1;
    int ntile = rem & 15;
    int n0 = ntile * BN;
    int kbase = ks * (I_ / 2);

    int cnt = counts[e];
    int m0 = mtile * BM;
    if (m0 >= cnt) return;

    __shared__ __align__(16) unsigned short As[4][BM][BKK];
    __shared__ __align__(16) unsigned short Bt[2][BN][BTW];

    int tid = threadIdx.x;
    int lane = tid & 63, wave = tid >> 6;
    int wm = wave >> 1, wn = wave & 1;

    int row0 = wave * 32 + (lane >> 2);
    const unsigned short* asrc0 = act + ((size_t)e * T_ + m0 + row0) * I_ + kbase + (lane & 3) * 8;
    const unsigned short* asrc1 = asrc0 + (size_t)16 * I_;

    int sn = tid & 127;
    int sk = (tid >> 7) * 16;
    const float* bcol = wdn + (size_t)e * I_ * H_ + (size_t)kbase * H_ + n0 + sn;
    const int ldbv = H_;

    f32x4 acc[4][4];
    #pragma unroll
    for (int mi = 0; mi < 4; mi++)
        #pragma unroll
        for (int ni = 0; ni < 4; ni++) acc[mi][ni] = (f32x4){0.f, 0.f, 0.f, 0.f};

    GEMM_PIPELINE(32)

    #pragma unroll
    for (int mi = 0; mi < 4; mi++) {
        #pragma unroll
        for (int ni = 0; ni < 4; ni++) {
            #pragma unroll
            for (int r = 0; r < 4; r++) {
                int rowe = wm * 64 + mi * 16 + (lane >> 4) * 4 + r;
                int grow = m0 + rowe;
                if (grow < cnt) {
                    int tok = tlist[e * T_ + grow];
                    float w = tw[e * T_ + grow];
                    int col = n0 + wn * 64 + ni * 16 + (lane & 15);
                    atomicAdd(&out[(size_t)tok * H_ + col], w * acc[mi][ni][r]);
                }
            }
        }
    }
}

// ---------------------------------------------------------------- launch
extern "C" void kernel_launch(void* const* d_in, const int* in_sizes, int n_in,
                              void* d_out, int out_size, void* d_ws, size_t ws_size,
                              hipStream_t stream)
{
    const float* x   = (const float*)d_in[0];
    const float* nw  = (const float*)d_in[1];
    const float* rw  = (const float*)d_in[2];
    const float* wgu = (const float*)d_in[3];
    const float* wdn = (const float*)d_in[4];
    float* out = (float*)d_out;

    char* ws = (char*)d_ws;
    unsigned short* tbf = (unsigned short*)ws;                       // 4 MB  [1024][2048] bf16
    unsigned short* act = (unsigned short*)(ws + (4u << 20));        // 32 MB [8][1024][2048] bf16
    int*   counts = (int*)(ws + (36u << 20));                        // 8 ints
    int*   tlist  = (int*)(ws + (36u << 20) + 256);                  // 8*1024 ints
    float* tw     = (float*)(ws + (36u << 20) + 256 + 8 * 1024 * 4); // 8*1024 floats

    int n = T_ * H_;
    zero_kernel<<<dim3((n + 255) / 256), 256, 0, stream>>>(out, n, counts);
    rms_router<<<dim3(T_), 256, 0, stream>>>(x, nw, rw, tbf, counts, tlist, tw);
    gu_gemm<<<dim3(2048), 256, 0, stream>>>(tbf, wgu, counts, tlist, act);
    down_gemm<<<dim3(2048), 256, 0, stream>>>(act, wdn, counts, tlist, tw, out);
}

// Round 10
// 189.344 us; speedup vs baseline: 2.3020x; 2.3020x over previous
//
#include <hip/hip_runtime.h>
#include <hip/hip_bf16.h>

#define H_   2048
#define E_   8
#define T_   1024
#define TWOI 4096
#define I_   2048
#define ALPHA 1.702f
#define LIMIT 7.0f

#define BM 128
#define BN 128
#define BKK 32
#define BTW 40   // bf16 B^T row length: 32 + 8 pad (80 B, 16B-aligned)

typedef __attribute__((ext_vector_type(8))) short short8;
typedef __attribute__((ext_vector_type(4))) float f32x4;

#define AS3U(p) ((__attribute__((address_space(3))) unsigned int*)(p))
#define AS1U(p) ((const __attribute__((address_space(1))) unsigned int*)(p))

__device__ __forceinline__ unsigned short f2bf(float f) {
    unsigned int u = __float_as_uint(f);
    u += 0x7fff + ((u >> 16) & 1);   // RTNE
    return (unsigned short)(u >> 16);
}

__device__ __forceinline__ unsigned int cvtpk_bf16(float lo, float hi) {
    unsigned int r;
    asm("v_cvt_pk_bf16_f32 %0, %1, %2" : "=v"(r) : "v"(lo), "v"(hi));
    return r;
}

// ---------------------------------------------------------------- zero counts
__global__ void zero_counts(int* __restrict__ counts) {
    int i = threadIdx.x;
    if (i < E_) counts[i] = 0;
}

// ---------------------------------------------------------------- rmsnorm + router
__global__ __launch_bounds__(256) void rms_router(
    const float* __restrict__ x, const float* __restrict__ nw,
    const float* __restrict__ rw,
    unsigned short* __restrict__ tbf, int* __restrict__ counts,
    int* __restrict__ tlist, int* __restrict__ tslot, float* __restrict__ tw)
{
    int t = blockIdx.x;
    int tid = threadIdx.x;
    int wave = tid >> 6, lane = tid & 63;
    const float* xr = x + (size_t)t * H_;

    float4 v0 = *(const float4*)(xr + tid * 4);
    float4 v1 = *(const float4*)(xr + 1024 + tid * 4);
    float ss = v0.x*v0.x + v0.y*v0.y + v0.z*v0.z + v0.w*v0.w
             + v1.x*v1.x + v1.y*v1.y + v1.z*v1.z + v1.w*v1.w;
    #pragma unroll
    for (int s = 32; s; s >>= 1) ss += __shfl_xor(ss, s);

    __shared__ float red[4];
    __shared__ float wlog[4][8];
    if (lane == 0) red[wave] = ss;
    __syncthreads();
    float total = red[0] + red[1] + red[2] + red[3];
    float scale = rsqrtf(total * (1.0f / H_) + 1e-5f);

    float4 n0 = *(const float4*)(nw + tid * 4);
    float4 n1 = *(const float4*)(nw + 1024 + tid * 4);
    float tv[8];
    tv[0] = v0.x * scale * n0.x; tv[1] = v0.y * scale * n0.y;
    tv[2] = v0.z * scale * n0.z; tv[3] = v0.w * scale * n0.w;
    tv[4] = v1.x * scale * n1.x; tv[5] = v1.y * scale * n1.y;
    tv[6] = v1.z * scale * n1.z; tv[7] = v1.w * scale * n1.w;

    ushort4 o0 = make_ushort4(f2bf(tv[0]), f2bf(tv[1]), f2bf(tv[2]), f2bf(tv[3]));
    ushort4 o1 = make_ushort4(f2bf(tv[4]), f2bf(tv[5]), f2bf(tv[6]), f2bf(tv[7]));
    *(ushort4*)(tbf + (size_t)t * H_ + tid * 4) = o0;
    *(ushort4*)(tbf + (size_t)t * H_ + 1024 + tid * 4) = o1;

    float acc[E_];
    #pragma unroll
    for (int e = 0; e < E_; e++) {
        const float* r0 = rw + (size_t)e * H_ + tid * 4;
        float4 a = *(const float4*)r0;
        float4 b = *(const float4*)(r0 + 1024);
        acc[e] = tv[0]*a.x + tv[1]*a.y + tv[2]*a.z + tv[3]*a.w
               + tv[4]*b.x + tv[5]*b.y + tv[6]*b.z + tv[7]*b.w;
    }
    #pragma unroll
    for (int s = 32; s; s >>= 1)
        #pragma unroll
        for (int e = 0; e < E_; e++) acc[e] += __shfl_xor(acc[e], s);
    if (lane == 0)
        #pragma unroll
        for (int e = 0; e < E_; e++) wlog[wave][e] = acc[e];
    __syncthreads();

    if (tid == 0) {
        float lg[E_];
        #pragma unroll
        for (int e = 0; e < E_; e++)
            lg[e] = wlog[0][e] + wlog[1][e] + wlog[2][e] + wlog[3][e];
        int i0 = 0;
        #pragma unroll
        for (int e = 1; e < E_; e++) if (lg[e] > lg[i0]) i0 = e;
        int i1 = -1;
        #pragma unroll
        for (int e = 0; e < E_; e++) {
            if (e == i0) continue;
            if (i1 < 0 || lg[e] > lg[i1]) i1 = e;
        }
        float e1 = expf(lg[i1] - lg[i0]);
        float s = 1.0f + e1;
        float w0 = 1.0f / s, w1 = e1 / s;
        int p0 = atomicAdd(&counts[i0], 1);
        tlist[i0 * T_ + p0] = t; tslot[i0 * T_ + p0] = 0; tw[i0 * T_ + p0] = w0;
        int p1 = atomicAdd(&counts[i1], 1);
        tlist[i1 * T_ + p1] = t; tslot[i1 * T_ + p1] = 1; tw[i1 * T_ + p1] = w1;
    }
}

// ---------------------------------------------------------------- shared GEMM machinery
// A: bf16 [BM][32] linear. B^T: bf16 [BN][BTW]. Both fragment reads are ds_read_b128.
__device__ __forceinline__ void compute_step(
    const unsigned short (*Asb)[BKK], const unsigned short (*Btb)[BTW],
    int wm, int wn, int lane, f32x4 acc[4][4])
{
    short8 a[4], b[4];
    int arow = wm * 64 + (lane & 15);
    int brow = wn * 64 + (lane & 15);
    int koff = (lane >> 4) * 8;
    #pragma unroll
    for (int mi = 0; mi < 4; mi++)
        a[mi] = *(const short8*)(&Asb[arow + mi * 16][koff]);
    #pragma unroll
    for (int ni = 0; ni < 4; ni++)
        b[ni] = *(const short8*)(&Btb[brow + ni * 16][koff]);
    #pragma unroll
    for (int mi = 0; mi < 4; mi++)
        #pragma unroll
        for (int ni = 0; ni < 4; ni++)
            acc[mi][ni] = __builtin_amdgcn_mfma_f32_16x16x32_bf16(a[mi], b[ni], acc[mi][ni], 0, 0, 0);
}

// One pipelined K-step, 2-ahead prefetch for both A (LDS DMA, 3 buffers) and
// B (registers -> bf16 ds_write, 2 buffers). 18 VMEM ops issued per step
// (2 global_load_lds + 16 B dwords); steady-state vmcnt(18) leaves the
// next tile's 18 in flight across the barrier.
#define STEP(TT, RCUR, RNEXT, PRE) {                                               \
    if (PRE) {                                                                     \
        int kk2_ = ((TT) + 2) * BKK;                                               \
        __builtin_amdgcn_global_load_lds(AS1U(asrc0 + kk2_), AS3U(&As[c2][wave * 32][0]), 16, 0, 0);      \
        __builtin_amdgcn_global_load_lds(AS1U(asrc1 + kk2_), AS3U(&As[c2][wave * 32 + 16][0]), 16, 0, 0); \
        _Pragma("unroll")                                                          \
        for (int j = 0; j < 16; j++)                                               \
            RNEXT[j] = bcol[(size_t)(kk2_ + sk + j) * ldbv];                       \
    }                                                                              \
    compute_step(As[c0], Bt[(TT) & 1], wm, wn, lane, acc);                         \
    {                                                                              \
        unsigned int pk_[8];                                                       \
        _Pragma("unroll")                                                          \
        for (int h = 0; h < 8; h++) pk_[h] = cvtpk_bf16(RCUR[2 * h], RCUR[2 * h + 1]); \
        unsigned short* db_ = &Bt[((TT) + 1) & 1][sn][sk];                         \
        *(uint4*)(db_)     = make_uint4(pk_[0], pk_[1], pk_[2], pk_[3]);           \
        *(uint4*)(db_ + 8) = make_uint4(pk_[4], pk_[5], pk_[6], pk_[7]);           \
    }                                                                              \
    if (PRE) { asm volatile("s_waitcnt vmcnt(18)" ::: "memory"); }                 \
    else     { asm volatile("s_waitcnt vmcnt(0)"  ::: "memory"); }                 \
    asm volatile("s_waitcnt lgkmcnt(0)" ::: "memory");                             \
    __builtin_amdgcn_sched_barrier(0);                                             \
    __builtin_amdgcn_s_barrier();                                                  \
    __builtin_amdgcn_sched_barrier(0);                                             \
    { int tmp_ = c0; c0 = c1; c1 = c2; c2 = tmp_; }                                \
}

// Full pipeline over NS K-steps (NS even, >= 4).
#define GEMM_PIPELINE(NS)                                                          \
    float r0[16], r1[16];                                                          \
    int c0 = 0, c1 = 1, c2 = 2;                                                    \
    /* prologue: A(0),B(0),A(1),B(1); write B(0) */                                \
    __builtin_amdgcn_global_load_lds(AS1U(asrc0), AS3U(&As[0][wave * 32][0]), 16, 0, 0);            \
    __builtin_amdgcn_global_load_lds(AS1U(asrc1), AS3U(&As[0][wave * 32 + 16][0]), 16, 0, 0);       \
    _Pragma("unroll")                                                              \
    for (int j = 0; j < 16; j++) r0[j] = bcol[(size_t)(sk + j) * ldbv];            \
    __builtin_amdgcn_global_load_lds(AS1U(asrc0 + BKK), AS3U(&As[1][wave * 32][0]), 16, 0, 0);      \
    __builtin_amdgcn_global_load_lds(AS1U(asrc1 + BKK), AS3U(&As[1][wave * 32 + 16][0]), 16, 0, 0); \
    _Pragma("unroll")                                                              \
    for (int j = 0; j < 16; j++) r1[j] = bcol[(size_t)(BKK + sk + j) * ldbv];      \
    {                                                                              \
        unsigned int pk_[8];                                                       \
        _Pragma("unroll")                                                          \
        for (int h = 0; h < 8; h++) pk_[h] = cvtpk_bf16(r0[2 * h], r0[2 * h + 1]); \
        unsigned short* db_ = &Bt[0][sn][sk];                                      \
        *(uint4*)(db_)     = make_uint4(pk_[0], pk_[1], pk_[2], pk_[3]);           \
        *(uint4*)(db_ + 8) = make_uint4(pk_[4], pk_[5], pk_[6], pk_[7]);           \
    }                                                                              \
    asm volatile("s_waitcnt vmcnt(18)" ::: "memory");                              \
    asm volatile("s_waitcnt lgkmcnt(0)" ::: "memory");                             \
    __builtin_amdgcn_sched_barrier(0);                                             \
    __builtin_amdgcn_s_barrier();                                                  \
    __builtin_amdgcn_sched_barrier(0);                                             \
    for (int t = 0; t < (NS) - 2; t += 2) {                                        \
        STEP(t,     r1, r0, 1)                                                     \
        STEP(t + 1, r0, r1, 1)                                                     \
    }                                                                              \
    STEP((NS) - 2, r1, r0, 0)                                                      \
    compute_step(As[c0], Bt[((NS) - 1) & 1], wm, wn, lane, acc);

// ---------------------------------------------------------------- GU GEMM + swiglu
__global__ __launch_bounds__(256, 3) void gu_gemm(
    const unsigned short* __restrict__ tbf,
    const float* __restrict__ wgu,
    const int* __restrict__ counts, const int* __restrict__ tlist,
    unsigned short* __restrict__ act)
{
    // Work-first ordering: mtile is the SLOWEST index so low bids (~mt 0-2)
    // are the working blocks, spread round-robin across all XCDs.
    // mtile twins of one (e,nt) are 256 apart -> same XCD (256 % 8 == 0).
    int bid = blockIdx.x;
    int mtile = bid >> 8;
    int rem = bid & 255;
    int e = rem >> 5;
    int n0 = (rem & 31) * BN;

    int cnt = counts[e];
    int m0 = mtile * BM;
    if (m0 >= cnt) return;

    __shared__ __align__(16) unsigned short As[3][BM][BKK];
    __shared__ __align__(16) unsigned short Bt[2][BN][BTW];

    int tid = threadIdx.x;
    int lane = tid & 63, wave = tid >> 6;
    int wm = wave >> 1, wn = wave & 1;

    int row0 = wave * 32 + (lane >> 2);
    int gr0 = m0 + row0, gr1 = gr0 + 16;
    int tok0 = tlist[e * T_ + (gr0 < cnt ? gr0 : 0)];
    int tok1 = tlist[e * T_ + (gr1 < cnt ? gr1 : 0)];
    const unsigned short* asrc0 = tbf + (size_t)tok0 * H_ + (lane & 3) * 8;
    const unsigned short* asrc1 = tbf + (size_t)tok1 * H_ + (lane & 3) * 8;

    // B column staging: thread covers column n0+sn, k-halves sk..sk+15
    int sn = tid & 127;
    int sk = (tid >> 7) * 16;
    const float* bcol = wgu + (size_t)e * H_ * TWOI + n0 + sn;
    const int ldbv = TWOI;

    f32x4 acc[4][4];
    #pragma unroll
    for (int mi = 0; mi < 4; mi++)
        #pragma unroll
        for (int ni = 0; ni < 4; ni++) acc[mi][ni] = (f32x4){0.f, 0.f, 0.f, 0.f};

    GEMM_PIPELINE(64)

    // epilogue: swiglu on column pairs (even=gate, odd=linear), write act bf16
    #pragma unroll
    for (int mi = 0; mi < 4; mi++) {
        #pragma unroll
        for (int ni = 0; ni < 4; ni++) {
            #pragma unroll
            for (int r = 0; r < 4; r++) {
                float v = acc[mi][ni][r];
                float p = __shfl_xor(v, 1);
                int rowe = wm * 64 + mi * 16 + (lane >> 4) * 4 + r;
                int grow = m0 + rowe;
                if (!(lane & 1) && grow < cnt) {
                    float glu = fminf(v, LIMIT);
                    float lin = fminf(fmaxf(p, -LIMIT), LIMIT);
                    float g = glu / (1.0f + __expf(-ALPHA * glu));
                    float a_ = g * (lin + 1.0f);
                    int col = n0 + wn * 64 + ni * 16 + (lane & 15);
                    act[((size_t)e * T_ + grow) * I_ + (col >> 1)] = f2bf(a_);
                }
            }
        }
    }
}

// ---------------------------------------------------------------- DOWN GEMM + slot-plane stores (K-split x2)
__global__ __launch_bounds__(256, 3) void down_gemm(
    const unsigned short* __restrict__ act,
    const float* __restrict__ wdn,
    const int* __restrict__ counts, const int* __restrict__ tlist,
    const int* __restrict__ tslot, const float* __restrict__ tw,
    float* __restrict__ parts)
{
    // Work-first ordering: mtile slowest; (e, ks, nt) fast.
    int bid = blockIdx.x;
    int mtile = bid >> 8;
    int rem = bid & 255;
    int e = rem >> 5;
    int ks = (rem >> 4) & 1;
    int ntile = rem & 15;
    int n0 = ntile * BN;
    int kbase = ks * (I_ / 2);

    int cnt = counts[e];
    int m0 = mtile * BM;
    if (m0 >= cnt) return;

    __shared__ __align__(16) unsigned short As[3][BM][BKK];
    __shared__ __align__(16) unsigned short Bt[2][BN][BTW];

    int tid = threadIdx.x;
    int lane = tid & 63, wave = tid >> 6;
    int wm = wave >> 1, wn = wave & 1;

    int row0 = wave * 32 + (lane >> 2);
    const unsigned short* asrc0 = act + ((size_t)e * T_ + m0 + row0) * I_ + kbase + (lane & 3) * 8;
    const unsigned short* asrc1 = asrc0 + (size_t)16 * I_;

    int sn = tid & 127;
    int sk = (tid >> 7) * 16;
    const float* bcol = wdn + (size_t)e * I_ * H_ + (size_t)kbase * H_ + n0 + sn;
    const int ldbv = H_;

    f32x4 acc[4][4];
    #pragma unroll
    for (int mi = 0; mi < 4; mi++)
        #pragma unroll
        for (int ni = 0; ni < 4; ni++) acc[mi][ni] = (f32x4){0.f, 0.f, 0.f, 0.f};

    GEMM_PIPELINE(32)

    #pragma unroll
    for (int mi = 0; mi < 4; mi++) {
        int rowe = wm * 64 + mi * 16 + (lane >> 4) * 4;
        int grow0 = m0 + rowe;
        #pragma unroll
        for (int r = 0; r < 4; r++) {
            int grow = grow0 + r;
            if (grow < cnt) {
                int tok  = tlist[e * T_ + grow];
                int slot = tslot[e * T_ + grow];
                float w  = tw[e * T_ + grow];
                float* dst = parts + ((size_t)(ks * 2 + slot) * T_ + tok) * H_;
                #pragma unroll
                for (int ni = 0; ni < 4; ni++) {
                    int col = n0 + wn * 64 + ni * 16 + (lane & 15);
                    dst[col] = w * acc[mi][ni][r];
                }
            }
        }
    }
}

// ---------------------------------------------------------------- combine 4 planes -> out
__global__ __launch_bounds__(256) void combine_kernel(
    const float* __restrict__ parts, float* __restrict__ out)
{
    int i = blockIdx.x * blockDim.x + threadIdx.x;   // float4 index over T*H/4
    const float4* p0 = (const float4*)parts;
    const float4* p1 = (const float4*)(parts + (size_t)T_ * H_);
    const float4* p2 = (const float4*)(parts + (size_t)2 * T_ * H_);
    const float4* p3 = (const float4*)(parts + (size_t)3 * T_ * H_);
    float4 a = p0[i], b = p1[i], c = p2[i], d = p3[i];
    float4 s;
    s.x = (a.x + b.x) + (c.x + d.x);
    s.y = (a.y + b.y) + (c.y + d.y);
    s.z = (a.z + b.z) + (c.z + d.z);
    s.w = (a.w + b.w) + (c.w + d.w);
    ((float4*)out)[i] = s;
}

// ---------------------------------------------------------------- launch
extern "C" void kernel_launch(void* const* d_in, const int* in_sizes, int n_in,
                              void* d_out, int out_size, void* d_ws, size_t ws_size,
                              hipStream_t stream)
{
    const float* x   = (const float*)d_in[0];
    const float* nw  = (const float*)d_in[1];
    const float* rw  = (const float*)d_in[2];
    const float* wgu = (const float*)d_in[3];
    const float* wdn = (const float*)d_in[4];
    float* out = (float*)d_out;

    char* ws = (char*)d_ws;
    unsigned short* tbf = (unsigned short*)ws;                   // 4 MB  [1024][2048] bf16
    unsigned short* act = (unsigned short*)(ws + (4u << 20));    // 32 MB [8][1024][2048] bf16
    float* parts = (float*)(ws + (36u << 20));                   // 32 MB [4][1024][2048] f32
    int*   counts = (int*)(ws + (68u << 20));                    // 8 ints
    int*   tlist  = (int*)(ws + (68u << 20) + 256);              // 8*1024 ints
    int*   tslot  = (int*)(ws + (68u << 20) + 256 + 32 * 1024);  // 8*1024 ints
    float* tw     = (float*)(ws + (68u << 20) + 256 + 64 * 1024);// 8*1024 floats

    zero_counts<<<dim3(1), 64, 0, stream>>>(counts);
    rms_router<<<dim3(T_), 256, 0, stream>>>(x, nw, rw, tbf, counts, tlist, tslot, tw);
    gu_gemm<<<dim3(2048), 256, 0, stream>>>(tbf, wgu, counts, tlist, act);
    down_gemm<<<dim3(2048), 256, 0, stream>>>(act, wdn, counts, tlist, tslot, tw, parts);
    combine_kernel<<<dim3((T_ * H_ / 4) / 256), 256, 0, stream>>>(parts, out);
}